// Round 13
// baseline (2528.088 us; speedup 1.0000x reference)
//
#include <hip/hip_runtime.h>

#define BB 16
#define NN 2048
#define NITERS 100

// k = log2(e)/eps, eps = 0.05
#define K2E      28.853900817779268f
#define TWO_K2E  57.707801635558536f
#define INV2K    0.017328679513998632f   // 1/(2k)
#define INV_K2E  0.034657359027997264f
#define INV4K    0.008664339756999316f   // 1/(4k)
#define LMU      (-11.0f)                // log2(1/2048)

#if __has_builtin(__builtin_amdgcn_exp2f)
#define EXP2F(x) __builtin_amdgcn_exp2f(x)
#else
#define EXP2F(x) exp2f(x)
#endif

typedef float v2f __attribute__((ext_vector_type(2)));
typedef float v4f __attribute__((ext_vector_type(4)));

// device-coherent (LLC-homed) accessors for the dual arrays
#define DSTORE(p, v) __hip_atomic_store((p), (v), __ATOMIC_RELAXED, __HIP_MEMORY_SCOPE_AGENT)
#define DLOAD(p)     __hip_atomic_load((p), __ATOMIC_RELAXED, __HIP_MEMORY_SCOPE_AGENT)

// verified multi-value butterfly: 8 partials -> full row-sum on lanes 0..7
// at row index rr = ((lane&1)<<2)|(lane&2)|((lane>>2)&1)
__device__ __forceinline__ float bfly8(const float acc[8], int lane) {
    const bool b0 = lane & 1, b1 = lane & 2, b2 = lane & 4;
    float v4[4], v2_[2], v1;
    #pragma unroll
    for (int i = 0; i < 4; ++i) {
        float recv = __shfl_xor(b0 ? acc[i] : acc[i+4], 1, 64);
        v4[i] = (b0 ? acc[i+4] : acc[i]) + recv;
    }
    #pragma unroll
    for (int i = 0; i < 2; ++i) {
        float recv = __shfl_xor(b1 ? v4[i] : v4[i+2], 2, 64);
        v2_[i] = (b1 ? v4[i+2] : v4[i]) + recv;
    }
    {
        float recv = __shfl_xor(b2 ? v2_[0] : v2_[1], 4, 64);
        v1 = (b2 ? v2_[1] : v2_[0]) + recv;
    }
    v1 += __shfl_xor(v1, 8, 64);
    v1 += __shfl_xor(v1, 16, 64);
    v1 += __shfl_xor(v1, 32, 64);
    return v1;
}

// R11-verified FULL-J sum-pass: each wave owns 8 rows x ALL 2048 j; dv from
// the per-phase LDS dual buffer on the fly. UNCHANGED.
__device__ __forceinline__ float sumpassF(
    const v4f* __restrict__ U, const v4f* __restrict__ T,
    const float* __restrict__ sdv,   // LDS dual buffer [0..NN)
    int rloc, int lane)
{
    v2f xp0[4], xp1[4], xp2[4], acc2[4];
    #pragma unroll
    for (int p = 0; p < 4; ++p) {
        const v4f ua = U[rloc + 2*p];
        const v4f ub = U[rloc + 2*p + 1];
        xp0[p] = (v2f){ua.x * INV2K, ub.x * INV2K};
        xp1[p] = (v2f){ua.y * INV2K, ub.y * INV2K};
        xp2[p] = (v2f){ua.z * INV2K, ub.z * INV2K};
        acc2[p] = (v2f){0.f, 0.f};
    }
    #pragma unroll 4
    for (int s = 0; s < 32; ++s) {
        const int p = lane + (s << 6);
        const v4f t = T[p];
        const float ad = sdv[p];
        const v2f a0v = (v2f){t.x, t.x}, a1v = (v2f){t.y, t.y};
        const v2f a2v = (v2f){t.z, t.z}, adv = (v2f){ad, ad};
        #pragma unroll
        for (int qq = 0; qq < 4; ++qq) {
            v2f d = __builtin_elementwise_fma(xp0[qq], a0v,
                    __builtin_elementwise_fma(xp1[qq], a1v,
                    __builtin_elementwise_fma(xp2[qq], a2v, adv)));
            acc2[qq] += (v2f){EXP2F(d.x), EXP2F(d.y)};
        }
    }
    float acc[8];
    #pragma unroll
    for (int p = 0; p < 4; ++p) { acc[2*p] = acc2[p].x; acc[2*p+1] = acc2[p].y; }
    return bfly8(acc, lane);   // lanes<8: full row-sum for row rloc + rr
}

// Epilogue partial: sum_j P_ij*C_ij, 8 rows x one j-half; AoS tables.
// (verified; two-jh-call composition verified) — wave-local. UNCHANGED.
__device__ __forceinline__ float epilA(
    const v4f* __restrict__ U, const v4f* __restrict__ T,
    const float* __restrict__ gB,
    float Aval, int rloc, int jh, int lane)
{
    const int jb = (jh << 10) + lane;
    float dv[16];
    #pragma unroll
    for (int s = 0; s < 16; ++s)
        dv[s] = DLOAD(gB + jb + (s << 6));

    float xr0[8], xr1[8], xr2[8], Ak[8], x2k[8];
    #pragma unroll
    for (int k = 0; k < 8; ++k) {
        const v4f u = U[rloc + k];
        xr0[k] = u.x * INV2K;
        xr1[k] = u.y * INV2K;
        xr2[k] = u.z * INV2K;
        const int src = ((k & 1) << 2) | (k & 2) | ((k >> 2) & 1);
        Ak[k]  = __shfl(Aval, src, 64);
        x2k[k] = K2E * (xr0[k]*xr0[k] + xr1[k]*xr1[k] + xr2[k]*xr2[k]);
    }
    float acc = 0.f;
    for (int s = 0; s < 16; ++s) {
        const v4f t = T[jb + (s << 6)];
        const float a0 = t.x, a1 = t.y, a2 = t.z, tb = dv[s];
        const float q2 = (a0*a0 + a1*a1 + a2*a2) * INV4K;   // k|y|^2
        #pragma unroll
        for (int k = 0; k < 8; ++k) {
            float d = fmaf(xr0[k], a0, fmaf(xr1[k], a1, fmaf(xr2[k], a2, tb)));
            float P = EXP2F(d + Ak[k]);                       // exp(logP)
            float C = fmaxf((x2k[k] + q2 - (d - tb)) * INV_K2E, 0.f);
            acc = fmaf(P, C, acc);
        }
    }
    return acc;
}

// R24: R11's geometry (256 blocks x 1024 thr, batch=blk>>4, 128 rows/block,
// full-j waves, 72 KB LDS) with the per-phase sync FUSED to 2 barriers:
//   barrier-1 : drains pass dual-DSTOREs; gates sd overwrite (all waves
//               finished READING sd in the pass before it)
//   tid0 release-posts the phase flag
//   ALL waves poll independently (16-slot ballot) — no broadcast barrier
//   each wave stages its own 128-float sd slice on poll exit (LLC latency
//   overlapped across waves' staggered poll exits)
//   barrier-2 : sd complete -> pass
// Was 4 barriers + w0-poll + serialized stage; now 2 barriers + overlapped
// stage. Flag protocol (release store / relaxed poll) identical to all
// verified rounds.
__global__ __launch_bounds__(1024, 4) void emd_sinkhornP(
    const float* __restrict__ x, const float* __restrict__ y,
    float* __restrict__ Af, float* __restrict__ Bf,
    int* __restrict__ flags, float* __restrict__ out)
{
    extern __shared__ float S[];     // sy(32KB) | sx(32KB) | sd(8KB) = 72 KB
    __shared__ float wsum[16];

    const int tid  = threadIdx.x;
    const int lane = tid & 63;
    const int w    = tid >> 6;        // 0..15
    const int blk  = blockIdx.x;
    const int b    = blk >> 4;        // batch 0..15
    const int q    = blk & 15;        // row-slab within batch (128 rows)
    const int base = b * NN;
    const int row0 = q * 128;
    const int rloc = row0 + w * 8;    // wave-owned 8 rows
    int* fb = flags + b * 64;         // 16 slots x 16 B per batch

    v4f   *sy = (v4f*)S;              // batch y (2k-scaled, AoS)
    v4f   *sx = (v4f*)S + NN;         // batch x
    float *sd = (float*)((v4f*)S + 2 * NN);   // staged duals [NN]

    // ---- prologue: stage 2k-scaled AoS tables for own batch ----
    #pragma unroll
    for (int v = 0; v < 2; ++v) {
        const int p = tid + (v << 10);
        const float* px = x + 3 * (size_t)(base + p);
        sx[p] = (v4f){TWO_K2E * px[0], TWO_K2E * px[1], TWO_K2E * px[2], 0.f};
        const float* py = y + 3 * (size_t)(base + p);
        sy[p] = (v4f){TWO_K2E * py[0], TWO_K2E * py[1], TWO_K2E * py[2], 0.f};
    }
    // ---- prologue: B0-init for own 128 columns ----
    if (tid < 128) {
        const int col = row0 + tid;
        const float* py = y + 3 * (size_t)(base + col);
        const float a = py[0], bb = py[1], c = py[2];
        DSTORE(&Bf[base + col], -K2E * (a*a + bb*bb + c*c));
    }

    // fused post + all-wave wait + distributed stage (2 barriers total)
    #define PWS(pval, tgt, gsrc) do {                                           \
        __syncthreads();   /* drain DSTOREs; all waves done reading sd */       \
        if (tid == 0)                                                           \
            __hip_atomic_store(fb + q * 4, (pval), __ATOMIC_RELEASE,            \
                               __HIP_MEMORY_SCOPE_AGENT);                       \
        for (;;) {                                                              \
            int vv = (lane < 16)                                                \
                ? __hip_atomic_load(fb + lane * 4, __ATOMIC_RELAXED,            \
                                    __HIP_MEMORY_SCOPE_AGENT)                   \
                : 0x7fffffff;                                                   \
            if (__ballot(vv >= (tgt)) == ~0ULL) break;                          \
            __builtin_amdgcn_s_sleep(1);                                        \
        }                                                                       \
        {   /* this wave's 128-float sd slice */                                \
            const int o_ = (w << 7) + lane;                                     \
            float a_ = DLOAD((gsrc) + o_);                                      \
            float b_ = DLOAD((gsrc) + o_ + 64);                                 \
            sd[o_] = a_; sd[o_ + 64] = b_;                                      \
        }                                                                       \
        __syncthreads();   /* sd complete */                                    \
    } while (0)

    const int rr = ((lane & 1) << 2) | (lane & 2) | ((lane >> 2) & 1);
    float Aval = 0.f;

    // initial: post B-init done (1), wait all, stage Bf
    PWS(1, 1, Bf + base);

    for (int it = 0; it < NITERS; ++it) {
        // ---- f phase: sd = Bf duals ----
        {
            float v1 = sumpassF(sx, sy, sd, rloc, lane);
            Aval = LMU - __log2f(v1);
            if (lane < 8) DSTORE(&Af[base + rloc + rr], Aval);
        }
        PWS(2 * it + 2, 2 * it + 2, Af + base);   // post f; wait; stage Af
        // ---- g phase: sd = Af duals ----
        {
            float v1 = sumpassF(sy, sx, sd, rloc, lane);
            if (lane < 8)
                DSTORE(&Bf[base + rloc + rr], LMU - __log2f(v1));
        }
        PWS(2 * it + 3, 2 * it + 3, Bf + base);   // post g; wait; stage Bf
    }
    // last PWS waited for 201 across the batch -> final Bf complete

    // ---- epilogue: wave-owned 8 rows x full j ----
    {
        float s = epilA(sx, sy, Bf + base, Aval, rloc, 0, lane)
                + epilA(sx, sy, Bf + base, Aval, rloc, 1, lane);
        #pragma unroll
        for (int m = 32; m > 0; m >>= 1) s += __shfl_xor(s, m, 64);
        if (lane == 0) wsum[w] = s;
        __syncthreads();
        if (tid == 0) {
            float t = 0.f;
            #pragma unroll
            for (int i = 0; i < 16; ++i) t += wsum[i];
            atomicAdd(out, t * (1.0f / (float)BB));
        }
    }
    #undef PWS
}

// =============== verified R11 kernel (2337 us) as launch fallback ===============
__global__ __launch_bounds__(1024, 4) void emd_sinkhornU(
    const float* __restrict__ x, const float* __restrict__ y,
    float* __restrict__ Af, float* __restrict__ Bf,
    int* __restrict__ flags, float* __restrict__ out)
{
    extern __shared__ float S[];     // 72 KB
    __shared__ float wsum[16];

    const int tid  = threadIdx.x;
    const int lane = tid & 63;
    const int w    = tid >> 6;
    const int blk  = blockIdx.x;
    const int b    = blk >> 4;
    const int q    = blk & 15;
    const int base = b * NN;
    const int row0 = q * 128;
    const int rloc = row0 + w * 8;
    int* fb = flags + 2048 + b * 64;  // upper flag region

    v4f   *sy = (v4f*)S;
    v4f   *sx = (v4f*)S + NN;
    float *sd = (float*)((v4f*)S + 2 * NN);

    #pragma unroll
    for (int v = 0; v < 2; ++v) {
        const int p = tid + (v << 10);
        const float* px = x + 3 * (size_t)(base + p);
        sx[p] = (v4f){TWO_K2E * px[0], TWO_K2E * px[1], TWO_K2E * px[2], 0.f};
        const float* py = y + 3 * (size_t)(base + p);
        sy[p] = (v4f){TWO_K2E * py[0], TWO_K2E * py[1], TWO_K2E * py[2], 0.f};
    }
    if (tid < 128) {
        const int col = row0 + tid;
        const float* py = y + 3 * (size_t)(base + col);
        const float a = py[0], bb = py[1], c = py[2];
        DSTORE(&Bf[base + col], -K2E * (a*a + bb*bb + c*c));
    }
    __syncthreads();
    if (tid == 0)
        __hip_atomic_store(fb + q * 4, 1, __ATOMIC_RELEASE, __HIP_MEMORY_SCOPE_AGENT);

    #define WAITB2(tgt) do { __syncthreads();                                   \
        if (w == 0) {                                                           \
            for (;;) {                                                          \
                int vv = (lane < 16)                                            \
                    ? __hip_atomic_load(fb + lane * 4, __ATOMIC_RELAXED,        \
                                        __HIP_MEMORY_SCOPE_AGENT)               \
                    : 0x7fffffff;                                               \
                if (__ballot(vv >= (tgt)) == ~0ULL) break;                      \
                __builtin_amdgcn_s_sleep(1);                                    \
            }                                                                   \
        }                                                                       \
        __syncthreads(); } while (0)

    #define POSTB2(pval) do { __syncthreads();                                  \
        if (tid == 0)                                                           \
            __hip_atomic_store(fb + q * 4, (pval), __ATOMIC_RELEASE,            \
                               __HIP_MEMORY_SCOPE_AGENT);                       \
    } while (0)

    #define STAGE2(gsrc) do {                                                   \
        float t0_ = DLOAD((gsrc) + tid);                                        \
        float t1_ = DLOAD((gsrc) + tid + 1024);                                 \
        sd[tid] = t0_; sd[tid + 1024] = t1_;                                    \
        __syncthreads(); } while (0)

    WAITB2(1);

    const int rr = ((lane & 1) << 2) | (lane & 2) | ((lane >> 2) & 1);
    float Aval = 0.f;

    for (int it = 0; it < NITERS; ++it) {
        STAGE2(Bf + base);
        {
            float v1 = sumpassF(sx, sy, sd, rloc, lane);
            Aval = LMU - __log2f(v1);
            if (lane < 8) DSTORE(&Af[base + rloc + rr], Aval);
        }
        POSTB2(2 * it + 2);
        WAITB2(2 * it + 2);
        STAGE2(Af + base);
        {
            float v1 = sumpassF(sy, sx, sd, rloc, lane);
            if (lane < 8)
                DSTORE(&Bf[base + rloc + rr], LMU - __log2f(v1));
        }
        POSTB2(2 * it + 3);
        WAITB2(2 * it + 3);
    }

    {
        float s = epilA(sx, sy, Bf + base, Aval, rloc, 0, lane)
                + epilA(sx, sy, Bf + base, Aval, rloc, 1, lane);
        #pragma unroll
        for (int m = 32; m > 0; m >>= 1) s += __shfl_xor(s, m, 64);
        if (lane == 0) wsum[w] = s;
        __syncthreads();
        if (tid == 0) {
            float t = 0.f;
            #pragma unroll
            for (int i = 0; i < 16; ++i) t += wsum[i];
            atomicAdd(out, t * (1.0f / (float)BB));
        }
    }
    #undef WAITB2
    #undef POSTB2
    #undef STAGE2
}

extern "C" void kernel_launch(void* const* d_in, const int* in_sizes, int n_in,
                              void* d_out, int out_size, void* d_ws, size_t ws_size,
                              hipStream_t stream) {
    const float* x = (const float*)d_in[0];
    const float* y = (const float*)d_in[1];
    float* out = (float*)d_out;
    char* ws = (char*)d_ws;

    int*   flags = (int*)ws;                                 // 16 KB (P: lower 4 KB; U: upper)
    float* Af    = (float*)(ws + 16384);                     // 128 KB
    float* Bf    = (float*)(ws + 16384 + (size_t)BB*NN*sizeof(float));

    hipMemsetAsync(flags, 0, 16384, stream);
    hipMemsetAsync(out, 0, sizeof(float), stream);

    void* args[] = {(void*)&x, (void*)&y, (void*)&Af, (void*)&Bf,
                    (void*)&flags, (void*)&out};

    const size_t shmem = (size_t)(2 * NN * 4 + NN) * sizeof(float);  // 72 KB
    // Preferred: fused-sync kernel (2 barriers/phase, distributed stage).
    hipError_t ep = hipFuncSetAttribute((const void*)emd_sinkhornP,
                        hipFuncAttributeMaxDynamicSharedMemorySize, (int)shmem);
    hipError_t e = (ep == hipSuccess)
        ? hipLaunchCooperativeKernel((const void*)emd_sinkhornP,
                                     dim3(256), dim3(1024), args, shmem, stream)
        : hipErrorInvalidValue;
    if (e != hipSuccess) {
        // Fallback: verified R11 kernel (2337 us)
        hipError_t eu = hipFuncSetAttribute((const void*)emd_sinkhornU,
                            hipFuncAttributeMaxDynamicSharedMemorySize, (int)shmem);
        hipError_t e2 = (eu == hipSuccess)
            ? hipLaunchCooperativeKernel((const void*)emd_sinkhornU,
                                         dim3(256), dim3(1024), args, shmem, stream)
            : hipErrorInvalidValue;
        if (e2 != hipSuccess) {
            hipLaunchKernelGGL(emd_sinkhornU, dim3(256), dim3(1024), shmem,
                               stream, x, y, Af, Bf, flags, out);
        }
    }
}

// Round 14
// 2342.444 us; speedup vs baseline: 1.0793x; 1.0793x over previous
//
#include <hip/hip_runtime.h>

#define BB 16
#define NN 2048
#define NITERS 100

// k = log2(e)/eps, eps = 0.05
#define K2E      28.853900817779268f
#define TWO_K2E  57.707801635558536f
#define INV2K    0.017328679513998632f   // 1/(2k)
#define INV_K2E  0.034657359027997264f
#define INV4K    0.008664339756999316f   // 1/(4k)
#define LMU      (-11.0f)                // log2(1/2048)

#if __has_builtin(__builtin_amdgcn_exp2f)
#define EXP2F(x) __builtin_amdgcn_exp2f(x)
#else
#define EXP2F(x) exp2f(x)
#endif

typedef float v2f __attribute__((ext_vector_type(2)));
typedef float v4f __attribute__((ext_vector_type(4)));

// device-coherent (LLC-homed) accessors for the dual arrays
#define DSTORE(p, v) __hip_atomic_store((p), (v), __ATOMIC_RELAXED, __HIP_MEMORY_SCOPE_AGENT)
#define DLOAD(p)     __hip_atomic_load((p), __ATOMIC_RELAXED, __HIP_MEMORY_SCOPE_AGENT)

// verified multi-value butterfly: 8 partials -> full row-sum on lanes 0..7
// at row index rr = ((lane&1)<<2)|(lane&2)|((lane>>2)&1)
__device__ __forceinline__ float bfly8(const float acc[8], int lane) {
    const bool b0 = lane & 1, b1 = lane & 2, b2 = lane & 4;
    float v4[4], v2_[2], v1;
    #pragma unroll
    for (int i = 0; i < 4; ++i) {
        float recv = __shfl_xor(b0 ? acc[i] : acc[i+4], 1, 64);
        v4[i] = (b0 ? acc[i+4] : acc[i]) + recv;
    }
    #pragma unroll
    for (int i = 0; i < 2; ++i) {
        float recv = __shfl_xor(b1 ? v4[i] : v4[i+2], 2, 64);
        v2_[i] = (b1 ? v4[i+2] : v4[i]) + recv;
    }
    {
        float recv = __shfl_xor(b2 ? v2_[0] : v2_[1], 4, 64);
        v1 = (b2 ? v2_[1] : v2_[0]) + recv;
    }
    v1 += __shfl_xor(v1, 8, 64);
    v1 += __shfl_xor(v1, 16, 64);
    v1 += __shfl_xor(v1, 32, 64);
    return v1;
}

// R11-verified FULL-J sum-pass: each wave owns 8 rows x ALL 2048 j; dv from
// the per-phase LDS dual buffer on the fly. UNCHANGED.
__device__ __forceinline__ float sumpassF(
    const v4f* __restrict__ U, const v4f* __restrict__ T,
    const float* __restrict__ sdv,   // LDS dual buffer [0..NN)
    int rloc, int lane)
{
    v2f xp0[4], xp1[4], xp2[4], acc2[4];
    #pragma unroll
    for (int p = 0; p < 4; ++p) {
        const v4f ua = U[rloc + 2*p];
        const v4f ub = U[rloc + 2*p + 1];
        xp0[p] = (v2f){ua.x * INV2K, ub.x * INV2K};
        xp1[p] = (v2f){ua.y * INV2K, ub.y * INV2K};
        xp2[p] = (v2f){ua.z * INV2K, ub.z * INV2K};
        acc2[p] = (v2f){0.f, 0.f};
    }
    #pragma unroll 4
    for (int s = 0; s < 32; ++s) {
        const int p = lane + (s << 6);
        const v4f t = T[p];
        const float ad = sdv[p];
        const v2f a0v = (v2f){t.x, t.x}, a1v = (v2f){t.y, t.y};
        const v2f a2v = (v2f){t.z, t.z}, adv = (v2f){ad, ad};
        #pragma unroll
        for (int qq = 0; qq < 4; ++qq) {
            v2f d = __builtin_elementwise_fma(xp0[qq], a0v,
                    __builtin_elementwise_fma(xp1[qq], a1v,
                    __builtin_elementwise_fma(xp2[qq], a2v, adv)));
            acc2[qq] += (v2f){EXP2F(d.x), EXP2F(d.y)};
        }
    }
    float acc[8];
    #pragma unroll
    for (int p = 0; p < 4; ++p) { acc[2*p] = acc2[p].x; acc[2*p+1] = acc2[p].y; }
    return bfly8(acc, lane);   // lanes<8: full row-sum for row rloc + rr
}

// Epilogue partial: sum_j P_ij*C_ij, 8 rows x one j-half; AoS tables.
// (verified; two-jh-call composition verified) — wave-local. UNCHANGED.
__device__ __forceinline__ float epilA(
    const v4f* __restrict__ U, const v4f* __restrict__ T,
    const float* __restrict__ gB,
    float Aval, int rloc, int jh, int lane)
{
    const int jb = (jh << 10) + lane;
    float dv[16];
    #pragma unroll
    for (int s = 0; s < 16; ++s)
        dv[s] = DLOAD(gB + jb + (s << 6));

    float xr0[8], xr1[8], xr2[8], Ak[8], x2k[8];
    #pragma unroll
    for (int k = 0; k < 8; ++k) {
        const v4f u = U[rloc + k];
        xr0[k] = u.x * INV2K;
        xr1[k] = u.y * INV2K;
        xr2[k] = u.z * INV2K;
        const int src = ((k & 1) << 2) | (k & 2) | ((k >> 2) & 1);
        Ak[k]  = __shfl(Aval, src, 64);
        x2k[k] = K2E * (xr0[k]*xr0[k] + xr1[k]*xr1[k] + xr2[k]*xr2[k]);
    }
    float acc = 0.f;
    for (int s = 0; s < 16; ++s) {
        const v4f t = T[jb + (s << 6)];
        const float a0 = t.x, a1 = t.y, a2 = t.z, tb = dv[s];
        const float q2 = (a0*a0 + a1*a1 + a2*a2) * INV4K;   // k|y|^2
        #pragma unroll
        for (int k = 0; k < 8; ++k) {
            float d = fmaf(xr0[k], a0, fmaf(xr1[k], a1, fmaf(xr2[k], a2, tb)));
            float P = EXP2F(d + Ak[k]);                       // exp(logP)
            float C = fmaxf((x2k[k] + q2 - (d - tb)) * INV_K2E, 0.f);
            acc = fmaf(P, C, acc);
        }
    }
    return acc;
}

// R25: R11 verbatim except POSTB+WAITB merged into the R9-proven PW shape
// (barrier -> tid0 release-store -> w0 poll -> barrier): 3 barriers/phase
// instead of 4. Sync protocol otherwise identical to the verified rounds:
// entry barrier drains the pass's dual DSTOREs before the flag posts;
// exit barrier precedes the STAGE; w0-only poll (all-wave polling
// regressed in R4/R13).
__global__ __launch_bounds__(1024, 4) void emd_sinkhornM(
    const float* __restrict__ x, const float* __restrict__ y,
    float* __restrict__ Af, float* __restrict__ Bf,
    int* __restrict__ flags, float* __restrict__ out)
{
    extern __shared__ float S[];     // sy(32KB) | sx(32KB) | sd(8KB) = 72 KB
    __shared__ float wsum[16];

    const int tid  = threadIdx.x;
    const int lane = tid & 63;
    const int w    = tid >> 6;        // 0..15
    const int blk  = blockIdx.x;
    const int b    = blk >> 4;        // batch 0..15
    const int q    = blk & 15;        // row-slab within batch (128 rows)
    const int base = b * NN;
    const int row0 = q * 128;
    const int rloc = row0 + w * 8;    // wave-owned 8 rows
    int* fb = flags + b * 64;         // 16 slots x 16 B per batch

    v4f   *sy = (v4f*)S;              // batch y (2k-scaled, AoS)
    v4f   *sx = (v4f*)S + NN;         // batch x
    float *sd = (float*)((v4f*)S + 2 * NN);   // staged duals [NN]

    // ---- prologue: stage 2k-scaled AoS tables for own batch ----
    #pragma unroll
    for (int v = 0; v < 2; ++v) {
        const int p = tid + (v << 10);
        const float* px = x + 3 * (size_t)(base + p);
        sx[p] = (v4f){TWO_K2E * px[0], TWO_K2E * px[1], TWO_K2E * px[2], 0.f};
        const float* py = y + 3 * (size_t)(base + p);
        sy[p] = (v4f){TWO_K2E * py[0], TWO_K2E * py[1], TWO_K2E * py[2], 0.f};
    }
    // ---- prologue: B0-init for own 128 columns ----
    if (tid < 128) {
        const int col = row0 + tid;
        const float* py = y + 3 * (size_t)(base + col);
        const float a = py[0], bb = py[1], c = py[2];
        DSTORE(&Bf[base + col], -K2E * (a*a + bb*bb + c*c));
    }

    // merged post + wait (R9-proven PW shape, 2 barriers):
    // barrier (drains DSTOREs) -> tid0 release-store -> w0 poll -> barrier
    #define PW2(pval, tgt) do { __syncthreads();                                \
        if (tid == 0)                                                           \
            __hip_atomic_store(fb + q * 4, (pval), __ATOMIC_RELEASE,            \
                               __HIP_MEMORY_SCOPE_AGENT);                       \
        if (w == 0) {                                                           \
            for (;;) {                                                          \
                int vv = (lane < 16)                                            \
                    ? __hip_atomic_load(fb + lane * 4, __ATOMIC_RELAXED,        \
                                        __HIP_MEMORY_SCOPE_AGENT)               \
                    : 0x7fffffff;                                               \
                if (__ballot(vv >= (tgt)) == ~0ULL) break;                      \
                __builtin_amdgcn_s_sleep(1);                                    \
            }                                                                   \
        }                                                                       \
        __syncthreads(); } while (0)

    // stage one dual array (LLC, coherent DLOAD) into sd[0..NN) (1 barrier)
    #define STAGE(gsrc) do {                                                    \
        float t0_ = DLOAD((gsrc) + tid);                                        \
        float t1_ = DLOAD((gsrc) + tid + 1024);                                 \
        sd[tid] = t0_; sd[tid + 1024] = t1_;                                    \
        __syncthreads(); } while (0)

    PW2(1, 1);                        // B-init posted + visible across batch

    const int rr = ((lane & 1) << 2) | (lane & 2) | ((lane >> 2) & 1);
    float Aval = 0.f;

    for (int it = 0; it < NITERS; ++it) {
        // ---- f phase: sd = Bf duals (complete per the wait just passed) ----
        STAGE(Bf + base);
        {
            float v1 = sumpassF(sx, sy, sd, rloc, lane);
            Aval = LMU - __log2f(v1);
            if (lane < 8) DSTORE(&Af[base + rloc + rr], Aval);
        }
        PW2(2 * it + 2, 2 * it + 2);  // post f; wait all peers' f
        // ---- g phase: sd = Af duals ----
        STAGE(Af + base);
        {
            float v1 = sumpassF(sy, sx, sd, rloc, lane);
            if (lane < 8)
                DSTORE(&Bf[base + rloc + rr], LMU - __log2f(v1));
        }
        PW2(2 * it + 3, 2 * it + 3);  // post g; wait all peers' g
    }
    // last PW2 (201) guarantees final Bf of the whole batch is complete

    // ---- epilogue: wave-owned 8 rows x full j ----
    {
        float s = epilA(sx, sy, Bf + base, Aval, rloc, 0, lane)
                + epilA(sx, sy, Bf + base, Aval, rloc, 1, lane);
        #pragma unroll
        for (int m = 32; m > 0; m >>= 1) s += __shfl_xor(s, m, 64);
        if (lane == 0) wsum[w] = s;
        __syncthreads();
        if (tid == 0) {
            float t = 0.f;
            #pragma unroll
            for (int i = 0; i < 16; ++i) t += wsum[i];
            atomicAdd(out, t * (1.0f / (float)BB));
        }
    }
    #undef PW2
    #undef STAGE
}

// =============== verified R11 kernel (2337 us) as launch fallback ===============
__global__ __launch_bounds__(1024, 4) void emd_sinkhornU(
    const float* __restrict__ x, const float* __restrict__ y,
    float* __restrict__ Af, float* __restrict__ Bf,
    int* __restrict__ flags, float* __restrict__ out)
{
    extern __shared__ float S[];     // 72 KB
    __shared__ float wsum[16];

    const int tid  = threadIdx.x;
    const int lane = tid & 63;
    const int w    = tid >> 6;
    const int blk  = blockIdx.x;
    const int b    = blk >> 4;
    const int q    = blk & 15;
    const int base = b * NN;
    const int row0 = q * 128;
    const int rloc = row0 + w * 8;
    int* fb = flags + 2048 + b * 64;  // upper flag region

    v4f   *sy = (v4f*)S;
    v4f   *sx = (v4f*)S + NN;
    float *sd = (float*)((v4f*)S + 2 * NN);

    #pragma unroll
    for (int v = 0; v < 2; ++v) {
        const int p = tid + (v << 10);
        const float* px = x + 3 * (size_t)(base + p);
        sx[p] = (v4f){TWO_K2E * px[0], TWO_K2E * px[1], TWO_K2E * px[2], 0.f};
        const float* py = y + 3 * (size_t)(base + p);
        sy[p] = (v4f){TWO_K2E * py[0], TWO_K2E * py[1], TWO_K2E * py[2], 0.f};
    }
    if (tid < 128) {
        const int col = row0 + tid;
        const float* py = y + 3 * (size_t)(base + col);
        const float a = py[0], bb = py[1], c = py[2];
        DSTORE(&Bf[base + col], -K2E * (a*a + bb*bb + c*c));
    }
    __syncthreads();
    if (tid == 0)
        __hip_atomic_store(fb + q * 4, 1, __ATOMIC_RELEASE, __HIP_MEMORY_SCOPE_AGENT);

    #define WAITB2(tgt) do { __syncthreads();                                   \
        if (w == 0) {                                                           \
            for (;;) {                                                          \
                int vv = (lane < 16)                                            \
                    ? __hip_atomic_load(fb + lane * 4, __ATOMIC_RELAXED,        \
                                        __HIP_MEMORY_SCOPE_AGENT)               \
                    : 0x7fffffff;                                               \
                if (__ballot(vv >= (tgt)) == ~0ULL) break;                      \
                __builtin_amdgcn_s_sleep(1);                                    \
            }                                                                   \
        }                                                                       \
        __syncthreads(); } while (0)

    #define POSTB2(pval) do { __syncthreads();                                  \
        if (tid == 0)                                                           \
            __hip_atomic_store(fb + q * 4, (pval), __ATOMIC_RELEASE,            \
                               __HIP_MEMORY_SCOPE_AGENT);                       \
    } while (0)

    #define STAGE2(gsrc) do {                                                   \
        float t0_ = DLOAD((gsrc) + tid);                                        \
        float t1_ = DLOAD((gsrc) + tid + 1024);                                 \
        sd[tid] = t0_; sd[tid + 1024] = t1_;                                    \
        __syncthreads(); } while (0)

    WAITB2(1);

    const int rr = ((lane & 1) << 2) | (lane & 2) | ((lane >> 2) & 1);
    float Aval = 0.f;

    for (int it = 0; it < NITERS; ++it) {
        STAGE2(Bf + base);
        {
            float v1 = sumpassF(sx, sy, sd, rloc, lane);
            Aval = LMU - __log2f(v1);
            if (lane < 8) DSTORE(&Af[base + rloc + rr], Aval);
        }
        POSTB2(2 * it + 2);
        WAITB2(2 * it + 2);
        STAGE2(Af + base);
        {
            float v1 = sumpassF(sy, sx, sd, rloc, lane);
            if (lane < 8)
                DSTORE(&Bf[base + rloc + rr], LMU - __log2f(v1));
        }
        POSTB2(2 * it + 3);
        WAITB2(2 * it + 3);
    }

    {
        float s = epilA(sx, sy, Bf + base, Aval, rloc, 0, lane)
                + epilA(sx, sy, Bf + base, Aval, rloc, 1, lane);
        #pragma unroll
        for (int m = 32; m > 0; m >>= 1) s += __shfl_xor(s, m, 64);
        if (lane == 0) wsum[w] = s;
        __syncthreads();
        if (tid == 0) {
            float t = 0.f;
            #pragma unroll
            for (int i = 0; i < 16; ++i) t += wsum[i];
            atomicAdd(out, t * (1.0f / (float)BB));
        }
    }
    #undef WAITB2
    #undef POSTB2
    #undef STAGE2
}

extern "C" void kernel_launch(void* const* d_in, const int* in_sizes, int n_in,
                              void* d_out, int out_size, void* d_ws, size_t ws_size,
                              hipStream_t stream) {
    const float* x = (const float*)d_in[0];
    const float* y = (const float*)d_in[1];
    float* out = (float*)d_out;
    char* ws = (char*)d_ws;

    int*   flags = (int*)ws;                                 // 16 KB (M: lower 4 KB; U: upper)
    float* Af    = (float*)(ws + 16384);                     // 128 KB
    float* Bf    = (float*)(ws + 16384 + (size_t)BB*NN*sizeof(float));

    hipMemsetAsync(flags, 0, 16384, stream);
    hipMemsetAsync(out, 0, sizeof(float), stream);

    void* args[] = {(void*)&x, (void*)&y, (void*)&Af, (void*)&Bf,
                    (void*)&flags, (void*)&out};

    const size_t shmem = (size_t)(2 * NN * 4 + NN) * sizeof(float);  // 72 KB
    // Preferred: merged post+wait kernel (3 barriers/phase).
    hipError_t em = hipFuncSetAttribute((const void*)emd_sinkhornM,
                        hipFuncAttributeMaxDynamicSharedMemorySize, (int)shmem);
    hipError_t e = (em == hipSuccess)
        ? hipLaunchCooperativeKernel((const void*)emd_sinkhornM,
                                     dim3(256), dim3(1024), args, shmem, stream)
        : hipErrorInvalidValue;
    if (e != hipSuccess) {
        // Fallback: verified R11 kernel (2337 us)
        hipError_t eu = hipFuncSetAttribute((const void*)emd_sinkhornU,
                            hipFuncAttributeMaxDynamicSharedMemorySize, (int)shmem);
        hipError_t e2 = (eu == hipSuccess)
            ? hipLaunchCooperativeKernel((const void*)emd_sinkhornU,
                                         dim3(256), dim3(1024), args, shmem, stream)
            : hipErrorInvalidValue;
        if (e2 != hipSuccess) {
            hipLaunchKernelGGL(emd_sinkhornU, dim3(256), dim3(1024), shmem,
                               stream, x, y, Af, Bf, flags, out);
        }
    }
}